// Round 1
// baseline (126.567 us; speedup 1.0000x reference)
//
#include <hip/hip_runtime.h>

// Problem constants (match reference setup_inputs)
constexpr int B_IMG = 8;
constexpr int A_N   = 120000;
constexpr int C_N   = 80;
constexpr int M_N   = 32;

constexpr float ALPHA = 0.25f;

// Kernel A (assign) geometry
constexpr int BLK_A = 256;
constexpr int NB_A  = (A_N + BLK_A - 1) / BLK_A;   // 469 blocks per image

// Kernel B (cls loss) geometry
constexpr int BLK_B       = 256;
constexpr int F4_PER_IMG  = A_N * C_N / 4;         // 2,400,000 float4 per image
constexpr int ITEMS_B     = 8;                      // float4s per thread
constexpr int NB_B  = (F4_PER_IMG + BLK_B * ITEMS_B - 1) / (BLK_B * ITEMS_B); // 1172

// ---------------------------------------------------------------------------
// Helpers
// ---------------------------------------------------------------------------
__device__ __forceinline__ float smooth_l1(float d) {
    d = fabsf(d);
    return (d <= (1.0f / 9.0f)) ? 4.5f * d * d : d - (0.5f / 9.0f);
}

__device__ __forceinline__ float loss_neg(float x) {
    // target == 0: (1-alpha) * p^2 * (-log(1-p))
    float p = fminf(fmaxf(x, 1e-4f), 0.9999f);
    return (1.0f - ALPHA) * p * p * (-__logf(1.0f - p));
}

__device__ __forceinline__ float loss_pos(float x) {
    // target == 1: alpha * (1-p)^2 * (-log(p))
    float p = fminf(fmaxf(x, 1e-4f), 0.9999f);
    float q = 1.0f - p;
    return ALPHA * q * q * (-__logf(p));
}

// ---------------------------------------------------------------------------
// Kernel A: per-anchor IoU/argmax -> code, reg loss, positive count
// ---------------------------------------------------------------------------
__global__ __launch_bounds__(BLK_A) void assign_kernel(
    const float* __restrict__ anchors,       // [A,4]
    const float* __restrict__ regressions,   // [B,A,4]
    const float* __restrict__ annotations,   // [B,M,5]
    signed char* __restrict__ codes,         // [B,A]
    float* __restrict__ regPart,             // [B,NB_A]
    float* __restrict__ nposPart)            // [B,NB_A]
{
    const int b = blockIdx.y;
    const int a = blockIdx.x * BLK_A + threadIdx.x;
    const float* __restrict__ ann = annotations + (size_t)b * M_N * 5; // uniform -> s_load

    float regl = 0.0f;
    bool positive = false;

    if (a < A_N) {
        const float4 anc = ((const float4*)anchors)[a];
        const float ax1 = anc.x, ay1 = anc.y, ax2 = anc.z, ay2 = anc.w;
        const float areaA = (ax2 - ax1) * (ay2 - ay1);

        // argmax over IoU via cross-multiplication (1 division total)
        float bi = -1.0f;   // best inter (sentinel: any valid beats it)
        float bu = 1.0f;    // best ua
        int   bm = -1;
        #pragma unroll 4
        for (int m = 0; m < M_N; ++m) {
            const float gx1 = ann[m * 5 + 0];
            const float gy1 = ann[m * 5 + 1];
            const float gx2 = ann[m * 5 + 2];
            const float gy2 = ann[m * 5 + 3];
            const bool valid = (ann[m * 5 + 4] != -1.0f);
            float iw = fminf(ax2, gx2) - fmaxf(ax1, gx1);
            float ih = fminf(ay2, gy2) - fmaxf(ay1, gy1);
            iw = fmaxf(iw, 0.0f);
            ih = fmaxf(ih, 0.0f);
            const float inter = iw * ih;
            const float areaB = (gx2 - gx1) * (gy2 - gy1);
            const float ua = fmaxf(areaA + areaB - inter, 1e-8f);
            // iou_m > iou_best  <=>  inter*bu > bi*ua   (ua,bu > 0)
            const bool better = valid && (inter * bu > bi * ua);
            if (better) { bi = inter; bu = ua; bm = m; }
        }

        const float iouMax = (bm >= 0) ? (bi / bu) : -1.0f;
        positive = (iouMax >= 0.5f);

        signed char code;
        if (iouMax < 0.4f)      code = -1;                                // negative: all targets 0
        else if (positive)      code = (signed char)(int)ann[bm * 5 + 4]; // gt class
        else                    code = -2;                                // ignore
        codes[(size_t)b * A_N + a] = code;

        if (positive) {
            const float aw  = ax2 - ax1;
            const float ah  = ay2 - ay1;
            const float acx = ax1 + 0.5f * aw;
            const float acy = ay1 + 0.5f * ah;
            const float gx1 = ann[bm * 5 + 0];
            const float gy1 = ann[bm * 5 + 1];
            const float gx2 = ann[bm * 5 + 2];
            const float gy2 = ann[bm * 5 + 3];
            float gw = gx2 - gx1;
            float gh = gy2 - gy1;
            const float gcx = gx1 + 0.5f * gw;
            const float gcy = gy1 + 0.5f * gh;
            gw = fmaxf(gw, 1.0f);
            gh = fmaxf(gh, 1.0f);
            const float t0 = ((gcx - acx) / aw) * 10.0f;  // / 0.1
            const float t1 = ((gcy - acy) / ah) * 10.0f;
            const float t2 = __logf(gw / aw) * 5.0f;      // / 0.2
            const float t3 = __logf(gh / ah) * 5.0f;
            const float4 rg = ((const float4*)regressions)[(size_t)b * A_N + a];
            regl = smooth_l1(t0 - rg.x) + smooth_l1(t1 - rg.y) +
                   smooth_l1(t2 - rg.z) + smooth_l1(t3 - rg.w);
        }
    }

    // block reduce (deterministic; partial written once per block -> no init pass)
    float rsum = regl;
    #pragma unroll
    for (int off = 32; off; off >>= 1) rsum += __shfl_down(rsum, off);
    const unsigned long long bal = __ballot(positive);

    __shared__ float wred[BLK_A / 64], wcnt[BLK_A / 64];
    const int wid = threadIdx.x >> 6;
    if ((threadIdx.x & 63) == 0) {
        wred[wid] = rsum;
        wcnt[wid] = (float)__popcll(bal);
    }
    __syncthreads();
    if (threadIdx.x == 0) {
        float r = 0.0f, p = 0.0f;
        #pragma unroll
        for (int w = 0; w < BLK_A / 64; ++w) { r += wred[w]; p += wcnt[w]; }
        regPart[b * NB_A + blockIdx.x]  = r;
        nposPart[b * NB_A + blockIdx.x] = p;
    }
}

// ---------------------------------------------------------------------------
// Kernel B: focal classification loss over [B,A,C] float4-streamed
// ---------------------------------------------------------------------------
__global__ __launch_bounds__(BLK_B) void cls_kernel(
    const float* __restrict__ cls,           // [B,A,C]
    const signed char* __restrict__ codes,   // [B,A]
    float* __restrict__ clsPart)             // [B,NB_B]
{
    const int b = blockIdx.y;
    const float4* __restrict__ src = (const float4*)(cls + (size_t)b * A_N * C_N);
    const signed char* __restrict__ cd = codes + (size_t)b * A_N;

    float sum = 0.0f;
    const int stride = NB_B * BLK_B;
    for (int idx = blockIdx.x * BLK_B + threadIdx.x; idx < F4_PER_IMG; idx += stride) {
        const float4 v = src[idx];
        const unsigned a = (unsigned)idx / 20u;      // C/4 == 20 chunks per anchor
        const int k = (int)((unsigned)idx % 20u) * 4; // first class index of chunk
        const int code = cd[a];
        if (code != -2) {  // -2: ignore -> contributes 0
            float s = loss_neg(v.x) + loss_neg(v.y) + loss_neg(v.z) + loss_neg(v.w);
            const int j = code - k;
            if ((unsigned)j < 4u) {  // this chunk holds the positive one-hot class
                const float x = (j == 0) ? v.x : (j == 1) ? v.y : (j == 2) ? v.z : v.w;
                s += loss_pos(x) - loss_neg(x);
            }
            sum += s;
        }
    }

    // block reduce -> one partial per block
    #pragma unroll
    for (int off = 32; off; off >>= 1) sum += __shfl_down(sum, off);
    __shared__ float wred[BLK_B / 64];
    const int wid = threadIdx.x >> 6;
    if ((threadIdx.x & 63) == 0) wred[wid] = sum;
    __syncthreads();
    if (threadIdx.x == 0) {
        float r = 0.0f;
        #pragma unroll
        for (int w = 0; w < BLK_B / 64; ++w) r += wred[w];
        clsPart[b * NB_B + blockIdx.x] = r;
    }
}

// ---------------------------------------------------------------------------
// Finalize: deterministic reduction of partials -> two scalars
// ---------------------------------------------------------------------------
__global__ __launch_bounds__(256) void finalize_kernel(
    const float* __restrict__ annotations,
    const float* __restrict__ clsPart,
    const float* __restrict__ regPart,
    const float* __restrict__ nposPart,
    float* __restrict__ out)
{
    __shared__ float red[256];
    const int t = threadIdx.x;
    float clsAcc = 0.0f, regAcc = 0.0f;

    for (int b = 0; b < B_IMG; ++b) {
        float s = 0.0f;
        for (int i = t; i < NB_B; i += 256) s += clsPart[b * NB_B + i];
        red[t] = s; __syncthreads();
        #pragma unroll
        for (int o = 128; o; o >>= 1) { if (t < o) red[t] += red[t + o]; __syncthreads(); }
        const float clsSum = red[0]; __syncthreads();

        s = 0.0f;
        for (int i = t; i < NB_A; i += 256) s += regPart[b * NB_A + i];
        red[t] = s; __syncthreads();
        #pragma unroll
        for (int o = 128; o; o >>= 1) { if (t < o) red[t] += red[t + o]; __syncthreads(); }
        const float regSum = red[0]; __syncthreads();

        s = 0.0f;
        for (int i = t; i < NB_A; i += 256) s += nposPart[b * NB_A + i];
        red[t] = s; __syncthreads();
        #pragma unroll
        for (int o = 128; o; o >>= 1) { if (t < o) red[t] += red[t + o]; __syncthreads(); }
        const float npos = red[0]; __syncthreads();

        bool has = false;
        for (int m = 0; m < M_N; ++m)
            has = has || (annotations[(size_t)b * M_N * 5 + m * 5 + 4] != -1.0f);

        const float cl = clsSum / fmaxf(npos, 1.0f);
        const float rl = (npos > 0.0f) ? regSum / (npos * 4.0f) : 0.0f;
        if (has) { clsAcc += cl; regAcc += rl; }
    }

    if (t == 0) {
        out[0] = clsAcc * (1.0f / B_IMG);
        out[1] = regAcc * (1.0f / B_IMG);
    }
}

// ---------------------------------------------------------------------------
// Launch
// ---------------------------------------------------------------------------
extern "C" void kernel_launch(void* const* d_in, const int* in_sizes, int n_in,
                              void* d_out, int out_size, void* d_ws, size_t ws_size,
                              hipStream_t stream) {
    const float* classifications = (const float*)d_in[0]; // [B,A,C]
    const float* regressions     = (const float*)d_in[1]; // [B,A,4]
    const float* anchors         = (const float*)d_in[2]; // [1,A,4]
    const float* annotations     = (const float*)d_in[3]; // [B,M,5]
    float* out = (float*)d_out;                           // [2]

    // Workspace layout (all partials written exactly once per call -> no init)
    float* clsPart  = (float*)d_ws;                       // B*NB_B
    float* regPart  = clsPart + (size_t)B_IMG * NB_B;     // B*NB_A
    float* nposPart = regPart + (size_t)B_IMG * NB_A;     // B*NB_A
    signed char* codes = (signed char*)(nposPart + (size_t)B_IMG * NB_A); // B*A

    assign_kernel<<<dim3(NB_A, B_IMG), BLK_A, 0, stream>>>(
        anchors, regressions, annotations, codes, regPart, nposPart);

    cls_kernel<<<dim3(NB_B, B_IMG), BLK_B, 0, stream>>>(
        classifications, codes, clsPart);

    finalize_kernel<<<1, 256, 0, stream>>>(
        annotations, clsPart, regPart, nposPart, out);
}

// Round 3
// 91.226 us; speedup vs baseline: 1.3874x; 1.3874x over previous
//
#include <hip/hip_runtime.h>

// Problem constants (match reference setup_inputs)
constexpr int B_IMG = 8;
constexpr int A_N   = 120000;
constexpr int C_N   = 80;
constexpr int M_N   = 32;

constexpr float ALPHA = 0.25f;

// Fused kernel geometry
constexpr int BLK   = 256;                         // threads per block
constexpr int APB   = 512;                         // anchors per block
constexpr int NBLK  = (A_N + APB - 1) / APB;       // 235 blocks per image
constexpr int F4PA  = C_N / 4;                     // 20 float4 per anchor

// ---------------------------------------------------------------------------
// Helpers
// ---------------------------------------------------------------------------
__device__ __forceinline__ float smooth_l1(float d) {
    d = fabsf(d);
    return (d <= (1.0f / 9.0f)) ? 4.5f * d * d : d - (0.5f / 9.0f);
}

__device__ __forceinline__ float loss_neg(float x) {
    // target == 0: (1-alpha) * p^2 * (-log(1-p))
    float p = fminf(fmaxf(x, 1e-4f), 0.9999f);
    return (1.0f - ALPHA) * p * p * (-__logf(1.0f - p));
}

__device__ __forceinline__ float loss_pos(float x) {
    // target == 1: alpha * (1-p)^2 * (-log(p))
    float p = fminf(fmaxf(x, 1e-4f), 0.9999f);
    float q = 1.0f - p;
    return ALPHA * q * q * (-__logf(p));
}

// Per-anchor assignment: IoU argmax vs 32 gt boxes (1 division), reg loss.
// Returns code: -1 negative (all targets 0), -2 ignore, 0..79 positive class.
__device__ __forceinline__ signed char assign_one(
    const float4 anc, const float* __restrict__ ann,
    const float4* __restrict__ regs, int b, int a,
    float& regl, int& pcount)
{
    const float ax1 = anc.x, ay1 = anc.y, ax2 = anc.z, ay2 = anc.w;
    const float areaA = (ax2 - ax1) * (ay2 - ay1);

    float bi = -1.0f;   // best inter (sentinel loses to any valid box)
    float bu = 1.0f;    // best ua
    int   bm = -1;
    #pragma unroll 4
    for (int m = 0; m < M_N; ++m) {
        const float gx1 = ann[m * 5 + 0];
        const float gy1 = ann[m * 5 + 1];
        const float gx2 = ann[m * 5 + 2];
        const float gy2 = ann[m * 5 + 3];
        const bool valid = (ann[m * 5 + 4] != -1.0f);
        float iw = fminf(ax2, gx2) - fmaxf(ax1, gx1);
        float ih = fminf(ay2, gy2) - fmaxf(ay1, gy1);
        iw = fmaxf(iw, 0.0f);
        ih = fmaxf(ih, 0.0f);
        const float inter = iw * ih;
        const float areaB = (gx2 - gx1) * (gy2 - gy1);
        const float ua = fmaxf(areaA + areaB - inter, 1e-8f);
        // iou_m > iou_best  <=>  inter*bu > bi*ua   (ua,bu > 0)
        const bool better = valid && (inter * bu > bi * ua);
        if (better) { bi = inter; bu = ua; bm = m; }
    }

    const float iouMax = (bm >= 0) ? (bi / bu) : -1.0f;
    const bool positive = (iouMax >= 0.5f);

    if (positive) {
        pcount += 1;
        const float aw  = ax2 - ax1;
        const float ah  = ay2 - ay1;
        const float acx = ax1 + 0.5f * aw;
        const float acy = ay1 + 0.5f * ah;
        const float gx1 = ann[bm * 5 + 0];
        const float gy1 = ann[bm * 5 + 1];
        const float gx2 = ann[bm * 5 + 2];
        const float gy2 = ann[bm * 5 + 3];
        float gw = gx2 - gx1;
        float gh = gy2 - gy1;
        const float gcx = gx1 + 0.5f * gw;
        const float gcy = gy1 + 0.5f * gh;
        gw = fmaxf(gw, 1.0f);
        gh = fmaxf(gh, 1.0f);
        const float t0 = ((gcx - acx) / aw) * 10.0f;  // / 0.1
        const float t1 = ((gcy - acy) / ah) * 10.0f;
        const float t2 = __logf(gw / aw) * 5.0f;      // / 0.2
        const float t3 = __logf(gh / ah) * 5.0f;
        const float4 rg = regs[(size_t)b * A_N + a];
        regl += smooth_l1(t0 - rg.x) + smooth_l1(t1 - rg.y) +
                smooth_l1(t2 - rg.z) + smooth_l1(t3 - rg.w);
    }

    if (iouMax < 0.4f) return -1;
    if (positive)      return (signed char)(int)ann[bm * 5 + 4];
    return -2;
}

// ---------------------------------------------------------------------------
// Fused kernel: assignment (phase 1, LDS codes) + focal cls stream (phase 2)
// ---------------------------------------------------------------------------
__global__ __launch_bounds__(BLK) void fused_kernel(
    const float* __restrict__ cls,           // [B,A,C]
    const float* __restrict__ regressions,   // [B,A,4]
    const float* __restrict__ anchors,       // [A,4]
    const float* __restrict__ annotations,   // [B,M,5]
    float* __restrict__ clsPart,             // [B*NBLK]
    float* __restrict__ regPart,             // [B*NBLK]
    float* __restrict__ nposPart)            // [B*NBLK]
{
    const int b    = blockIdx.y;
    const int base = blockIdx.x * APB;                 // first anchor of block
    const int nA   = min(APB, A_N - base);             // anchors in this block
    const float* __restrict__ ann = annotations + (size_t)b * M_N * 5; // uniform
    const float4* __restrict__ regs = (const float4*)regressions;

    __shared__ signed char scode[APB];

    // ---- phase 1: assignment for anchors [base, base+nA), 2 per thread ----
    float regl = 0.0f;
    int   pcnt = 0;
    const int t = threadIdx.x;
    #pragma unroll
    for (int s = 0; s < APB; s += BLK) {
        const int li = s + t;
        const int a  = base + li;
        signed char c = -2;  // out-of-range: ignore (phase-2 bound skips anyway)
        if (li < nA) {
            const float4 anc = ((const float4*)anchors)[a];
            c = assign_one(anc, ann, regs, b, a, regl, pcnt);
        }
        scode[li] = c;
    }
    __syncthreads();

    // ---- phase 2: stream classifications for these anchors ----
    const float4* __restrict__ src =
        (const float4*)(cls + (size_t)b * A_N * C_N) + (size_t)base * F4PA;
    const int nF4 = nA * F4PA;                         // <= 10240
    float csum = 0.0f;
    for (int idx = t; idx < nF4; idx += BLK) {
        const float4 v = src[idx];
        const int al = (int)((unsigned)idx / 20u);     // local anchor
        const int k  = (int)((unsigned)idx % 20u) * 4; // first class of chunk
        const int code = scode[al];
        if (code != -2) {  // -2: ignore row -> contributes 0
            float s = loss_neg(v.x) + loss_neg(v.y) + loss_neg(v.z) + loss_neg(v.w);
            const int j = code - k;
            if ((unsigned)j < 4u) {  // chunk holds the one-hot positive class
                const float x = (j == 0) ? v.x : (j == 1) ? v.y : (j == 2) ? v.z : v.w;
                s += loss_pos(x) - loss_neg(x);
            }
            csum += s;
        }
    }

    // ---- block reduce (deterministic, one write per block) ----
    float r = regl, p = (float)pcnt, c = csum;
    #pragma unroll
    for (int off = 32; off; off >>= 1) {
        r += __shfl_down(r, off);
        p += __shfl_down(p, off);
        c += __shfl_down(c, off);
    }
    __shared__ float wr[BLK / 64], wp[BLK / 64], wc[BLK / 64];
    const int wid = t >> 6;
    if ((t & 63) == 0) { wr[wid] = r; wp[wid] = p; wc[wid] = c; }
    __syncthreads();
    if (t == 0) {
        float rr = 0.0f, pp = 0.0f, cc = 0.0f;
        #pragma unroll
        for (int w = 0; w < BLK / 64; ++w) { rr += wr[w]; pp += wp[w]; cc += wc[w]; }
        const int pidx = b * NBLK + blockIdx.x;
        clsPart[pidx]  = cc;
        regPart[pidx]  = rr;
        nposPart[pidx] = pp;
    }
}

// ---------------------------------------------------------------------------
// Finalize: one wave per image, shfl reduce of NBLK partials -> two scalars
// ---------------------------------------------------------------------------
__global__ __launch_bounds__(64 * B_IMG) void finalize_kernel(
    const float* __restrict__ annotations,
    const float* __restrict__ clsPart,
    const float* __restrict__ regPart,
    const float* __restrict__ nposPart,
    float* __restrict__ out)
{
    const int w    = threadIdx.x >> 6;   // image
    const int lane = threadIdx.x & 63;

    float c = 0.0f, r = 0.0f, p = 0.0f;
    for (int i = lane; i < NBLK; i += 64) {
        const int idx = w * NBLK + i;
        c += clsPart[idx];
        r += regPart[idx];
        p += nposPart[idx];
    }
    #pragma unroll
    for (int off = 32; off; off >>= 1) {
        c += __shfl_down(c, off);
        r += __shfl_down(r, off);
        p += __shfl_down(p, off);
    }

    __shared__ float sc[B_IMG], sr[B_IMG];
    if (lane == 0) {
        bool has = false;
        for (int m = 0; m < M_N; ++m)
            has = has || (annotations[(size_t)w * M_N * 5 + m * 5 + 4] != -1.0f);
        const float cl = c / fmaxf(p, 1.0f);
        const float rl = (p > 0.0f) ? r / (p * 4.0f) : 0.0f;
        sc[w] = has ? cl : 0.0f;
        sr[w] = has ? rl : 0.0f;
    }
    __syncthreads();
    if (threadIdx.x == 0) {
        float ca = 0.0f, ra = 0.0f;
        #pragma unroll
        for (int i = 0; i < B_IMG; ++i) { ca += sc[i]; ra += sr[i]; }
        out[0] = ca * (1.0f / B_IMG);
        out[1] = ra * (1.0f / B_IMG);
    }
}

// ---------------------------------------------------------------------------
// Launch
// ---------------------------------------------------------------------------
extern "C" void kernel_launch(void* const* d_in, const int* in_sizes, int n_in,
                              void* d_out, int out_size, void* d_ws, size_t ws_size,
                              hipStream_t stream) {
    const float* classifications = (const float*)d_in[0]; // [B,A,C]
    const float* regressions     = (const float*)d_in[1]; // [B,A,4]
    const float* anchors         = (const float*)d_in[2]; // [1,A,4]
    const float* annotations     = (const float*)d_in[3]; // [B,M,5]
    float* out = (float*)d_out;                           // [2]

    // Workspace: partials written exactly once per call -> no init pass
    float* clsPart  = (float*)d_ws;                        // B*NBLK
    float* regPart  = clsPart + (size_t)B_IMG * NBLK;      // B*NBLK
    float* nposPart = regPart + (size_t)B_IMG * NBLK;      // B*NBLK

    fused_kernel<<<dim3(NBLK, B_IMG), BLK, 0, stream>>>(
        classifications, regressions, anchors, annotations,
        clsPart, regPart, nposPart);

    finalize_kernel<<<1, 64 * B_IMG, 0, stream>>>(
        annotations, clsPart, regPart, nposPart, out);
}

// Round 4
// 78.071 us; speedup vs baseline: 1.6212x; 1.1685x over previous
//
#include <hip/hip_runtime.h>

// Problem constants (match reference setup_inputs)
constexpr int B_IMG = 8;
constexpr int A_N   = 120000;
constexpr int C_N   = 80;
constexpr int M_N   = 32;

constexpr float ALPHA = 0.25f;

// Fused kernel geometry
constexpr int BLK    = 256;                        // threads per block
constexpr int APB    = 512;                        // anchors per block
constexpr int NBLK   = (A_N + APB - 1) / APB;      // 235 blocks per image
constexpr int F4PA   = C_N / 4;                    // 20 float4 per anchor
constexpr int UNROLL = 8;                          // float4 loads in flight/thread
// full block: nF4 = 512*20 = 10240 = 5 * (BLK*UNROLL)  -> exact fast path
constexpr int FAST_ITERS = (APB * F4PA) / (BLK * UNROLL);

// ---------------------------------------------------------------------------
// Helpers
// ---------------------------------------------------------------------------
__device__ __forceinline__ float smooth_l1(float d) {
    d = fabsf(d);
    return (d <= (1.0f / 9.0f)) ? 4.5f * d * d : d - (0.5f / 9.0f);
}

__device__ __forceinline__ float loss_neg(float x) {
    // target == 0: (1-alpha) * p^2 * (-log(1-p))
    float p = fminf(fmaxf(x, 1e-4f), 0.9999f);
    return (1.0f - ALPHA) * p * p * (-__logf(1.0f - p));
}

__device__ __forceinline__ float loss_pos(float x) {
    // target == 1: alpha * (1-p)^2 * (-log(p))
    float p = fminf(fmaxf(x, 1e-4f), 0.9999f);
    float q = 1.0f - p;
    return ALPHA * q * q * (-__logf(p));
}

// Per-anchor assignment: IoU argmax vs 32 gt boxes (1 division), reg loss.
// Returns code: -1 negative (all targets 0), -2 ignore, 0..79 positive class.
__device__ __forceinline__ signed char assign_one(
    const float4 anc, const float* __restrict__ ann,
    const float4* __restrict__ regs, int b, int a,
    float& regl, int& pcount)
{
    const float ax1 = anc.x, ay1 = anc.y, ax2 = anc.z, ay2 = anc.w;
    const float areaA = (ax2 - ax1) * (ay2 - ay1);

    float bi = -1.0f;   // best inter (sentinel loses to any valid box)
    float bu = 1.0f;    // best ua
    int   bm = -1;
    #pragma unroll 2
    for (int m = 0; m < M_N; ++m) {
        const float gx1 = ann[m * 5 + 0];
        const float gy1 = ann[m * 5 + 1];
        const float gx2 = ann[m * 5 + 2];
        const float gy2 = ann[m * 5 + 3];
        const bool valid = (ann[m * 5 + 4] != -1.0f);
        float iw = fminf(ax2, gx2) - fmaxf(ax1, gx1);
        float ih = fminf(ay2, gy2) - fmaxf(ay1, gy1);
        iw = fmaxf(iw, 0.0f);
        ih = fmaxf(ih, 0.0f);
        const float inter = iw * ih;
        const float areaB = (gx2 - gx1) * (gy2 - gy1);
        const float ua = fmaxf(areaA + areaB - inter, 1e-8f);
        // iou_m > iou_best  <=>  inter*bu > bi*ua   (ua,bu > 0)
        const bool better = valid && (inter * bu > bi * ua);
        if (better) { bi = inter; bu = ua; bm = m; }
    }

    const float iouMax = (bm >= 0) ? (bi / bu) : -1.0f;
    const bool positive = (iouMax >= 0.5f);

    if (positive) {
        pcount += 1;
        const float aw  = ax2 - ax1;
        const float ah  = ay2 - ay1;
        const float acx = ax1 + 0.5f * aw;
        const float acy = ay1 + 0.5f * ah;
        const float gx1 = ann[bm * 5 + 0];
        const float gy1 = ann[bm * 5 + 1];
        const float gx2 = ann[bm * 5 + 2];
        const float gy2 = ann[bm * 5 + 3];
        float gw = gx2 - gx1;
        float gh = gy2 - gy1;
        const float gcx = gx1 + 0.5f * gw;
        const float gcy = gy1 + 0.5f * gh;
        gw = fmaxf(gw, 1.0f);
        gh = fmaxf(gh, 1.0f);
        const float t0 = ((gcx - acx) / aw) * 10.0f;  // / 0.1
        const float t1 = ((gcy - acy) / ah) * 10.0f;
        const float t2 = __logf(gw / aw) * 5.0f;      // / 0.2
        const float t3 = __logf(gh / ah) * 5.0f;
        const float4 rg = regs[(size_t)b * A_N + a];
        regl += smooth_l1(t0 - rg.x) + smooth_l1(t1 - rg.y) +
                smooth_l1(t2 - rg.z) + smooth_l1(t3 - rg.w);
    }

    if (iouMax < 0.4f) return -1;
    if (positive)      return (signed char)(int)ann[bm * 5 + 4];
    return -2;
}

// ---------------------------------------------------------------------------
// Fused kernel:
//   phase 1: assignment -> LDS code + LDS float mask (1.0 keep / 0.0 ignore)
//   phase 2: rare one-hot positive corrections (scalar reads)
//   phase 3: branchless masked focal stream, 8 float4 loads in flight
// ---------------------------------------------------------------------------
__global__ __launch_bounds__(BLK, 4) void fused_kernel(
    const float* __restrict__ cls,           // [B,A,C]
    const float* __restrict__ regressions,   // [B,A,4]
    const float* __restrict__ anchors,       // [A,4]
    const float* __restrict__ annotations,   // [B,M,5]
    float* __restrict__ clsPart,             // [B*NBLK]
    float* __restrict__ regPart,             // [B*NBLK]
    float* __restrict__ nposPart)            // [B*NBLK]
{
    const int b    = blockIdx.y;
    const int base = blockIdx.x * APB;                 // first anchor of block
    const int nA   = min(APB, A_N - base);             // anchors in this block
    const float* __restrict__ ann = annotations + (size_t)b * M_N * 5; // uniform
    const float4* __restrict__ regs = (const float4*)regressions;

    __shared__ signed char scode[APB];
    __shared__ float       smask[APB];

    // ---- phase 1: assignment, 2 anchors per thread (NOT unrolled: VGPRs) ----
    float regl = 0.0f;
    int   pcnt = 0;
    const int t = threadIdx.x;
    #pragma unroll 1
    for (int s = 0; s < APB; s += BLK) {
        const int li = s + t;
        const int a  = base + li;
        signed char c = -2;  // out-of-range / ignore
        if (li < nA) {
            const float4 anc = ((const float4*)anchors)[a];
            c = assign_one(anc, ann, regs, b, a, regl, pcnt);
        }
        scode[li] = c;
        smask[li] = (c != -2) ? 1.0f : 0.0f;
    }
    __syncthreads();

    const float* __restrict__ rowbase = cls + (size_t)(b * A_N + base) * C_N;
    float csum = 0.0f;

    // ---- phase 2: positive one-hot corrections (rare scalar reads) ----
    #pragma unroll 1
    for (int s = 0; s < APB; s += BLK) {
        const int li = s + t;
        const int code = scode[li];
        if (code >= 0) {
            const float x = rowbase[(size_t)li * C_N + code];
            csum += loss_pos(x) - loss_neg(x);
        }
    }

    // ---- phase 3: branchless masked stream of this block's cls chunk ----
    const float4* __restrict__ src = (const float4*)rowbase;
    if (nA == APB) {
        // fast path: exactly FAST_ITERS super-iterations, 8 loads in flight
        const float4* p = src + t;
        #pragma unroll 1
        for (int it = 0; it < FAST_ITERS; ++it) {
            float4 v[UNROLL];
            #pragma unroll
            for (int u = 0; u < UNROLL; ++u) v[u] = p[u * BLK];
            const int ibase = it * (BLK * UNROLL) + t;
            #pragma unroll
            for (int u = 0; u < UNROLL; ++u) {
                const unsigned idx = (unsigned)(ibase + u * BLK);
                const float m = smask[idx / 20u];
                csum += m * (loss_neg(v[u].x) + loss_neg(v[u].y) +
                             loss_neg(v[u].z) + loss_neg(v[u].w));
            }
            p += BLK * UNROLL;
        }
    } else {
        // tail block: simple masked loop
        const int nF4 = nA * F4PA;
        for (int idx = t; idx < nF4; idx += BLK) {
            const float4 v = src[idx];
            const float m = smask[(unsigned)idx / 20u];
            csum += m * (loss_neg(v.x) + loss_neg(v.y) +
                         loss_neg(v.z) + loss_neg(v.w));
        }
    }

    // ---- block reduce (deterministic, one write per block) ----
    float r = regl, p = (float)pcnt, c = csum;
    #pragma unroll
    for (int off = 32; off; off >>= 1) {
        r += __shfl_down(r, off);
        p += __shfl_down(p, off);
        c += __shfl_down(c, off);
    }
    __shared__ float wr[BLK / 64], wp[BLK / 64], wc[BLK / 64];
    const int wid = t >> 6;
    if ((t & 63) == 0) { wr[wid] = r; wp[wid] = p; wc[wid] = c; }
    __syncthreads();
    if (t == 0) {
        float rr = 0.0f, pp = 0.0f, cc = 0.0f;
        #pragma unroll
        for (int w = 0; w < BLK / 64; ++w) { rr += wr[w]; pp += wp[w]; cc += wc[w]; }
        const int pidx = b * NBLK + blockIdx.x;
        clsPart[pidx]  = cc;
        regPart[pidx]  = rr;
        nposPart[pidx] = pp;
    }
}

// ---------------------------------------------------------------------------
// Finalize: one wave per image, shfl reduce of NBLK partials -> two scalars
// ---------------------------------------------------------------------------
__global__ __launch_bounds__(64 * B_IMG) void finalize_kernel(
    const float* __restrict__ annotations,
    const float* __restrict__ clsPart,
    const float* __restrict__ regPart,
    const float* __restrict__ nposPart,
    float* __restrict__ out)
{
    const int w    = threadIdx.x >> 6;   // image
    const int lane = threadIdx.x & 63;

    float c = 0.0f, r = 0.0f, p = 0.0f;
    for (int i = lane; i < NBLK; i += 64) {
        const int idx = w * NBLK + i;
        c += clsPart[idx];
        r += regPart[idx];
        p += nposPart[idx];
    }
    #pragma unroll
    for (int off = 32; off; off >>= 1) {
        c += __shfl_down(c, off);
        r += __shfl_down(r, off);
        p += __shfl_down(p, off);
    }

    __shared__ float sc[B_IMG], sr[B_IMG];
    if (lane == 0) {
        bool has = false;
        for (int m = 0; m < M_N; ++m)
            has = has || (annotations[(size_t)w * M_N * 5 + m * 5 + 4] != -1.0f);
        const float cl = c / fmaxf(p, 1.0f);
        const float rl = (p > 0.0f) ? r / (p * 4.0f) : 0.0f;
        sc[w] = has ? cl : 0.0f;
        sr[w] = has ? rl : 0.0f;
    }
    __syncthreads();
    if (threadIdx.x == 0) {
        float ca = 0.0f, ra = 0.0f;
        #pragma unroll
        for (int i = 0; i < B_IMG; ++i) { ca += sc[i]; ra += sr[i]; }
        out[0] = ca * (1.0f / B_IMG);
        out[1] = ra * (1.0f / B_IMG);
    }
}

// ---------------------------------------------------------------------------
// Launch
// ---------------------------------------------------------------------------
extern "C" void kernel_launch(void* const* d_in, const int* in_sizes, int n_in,
                              void* d_out, int out_size, void* d_ws, size_t ws_size,
                              hipStream_t stream) {
    const float* classifications = (const float*)d_in[0]; // [B,A,C]
    const float* regressions     = (const float*)d_in[1]; // [B,A,4]
    const float* anchors         = (const float*)d_in[2]; // [1,A,4]
    const float* annotations     = (const float*)d_in[3]; // [B,M,5]
    float* out = (float*)d_out;                           // [2]

    // Workspace: partials written exactly once per call -> no init pass
    float* clsPart  = (float*)d_ws;                        // B*NBLK
    float* regPart  = clsPart + (size_t)B_IMG * NBLK;      // B*NBLK
    float* nposPart = regPart + (size_t)B_IMG * NBLK;      // B*NBLK

    fused_kernel<<<dim3(NBLK, B_IMG), BLK, 0, stream>>>(
        classifications, regressions, anchors, annotations,
        clsPart, regPart, nposPart);

    finalize_kernel<<<1, 64 * B_IMG, 0, stream>>>(
        annotations, clsPart, regPart, nposPart, out);
}

// Round 5
// 74.224 us; speedup vs baseline: 1.7052x; 1.0518x over previous
//
#include <hip/hip_runtime.h>

// Problem constants (match reference setup_inputs)
constexpr int B_IMG = 8;
constexpr int A_N   = 120000;
constexpr int C_N   = 80;
constexpr int M_N   = 32;

constexpr float ALPHA = 0.25f;

// Fused kernel geometry
constexpr int BLK  = 256;                          // threads per block (4 waves)
constexpr int APB  = 512;                          // anchors per block
constexpr int NBLK = (A_N + APB - 1) / APB;        // 235 blocks per image
constexpr int F4PA = C_N / 4;                      // 20 float4 per anchor
constexpr int U    = 4;                            // float4 per thread per quad
constexpr int F4_PER_IT = BLK * U;                 // 1024 float4 per iteration
constexpr int NIT  = (APB * F4PA) / F4_PER_IT;     // 10 iterations (even)

typedef float f4v __attribute__((ext_vector_type(4)));

__device__ __forceinline__ f4v ntload(const f4v* p) {
    return __builtin_nontemporal_load(p);
}

// ---------------------------------------------------------------------------
// Helpers
// ---------------------------------------------------------------------------
__device__ __forceinline__ float smooth_l1(float d) {
    d = fabsf(d);
    return (d <= (1.0f / 9.0f)) ? 4.5f * d * d : d - (0.5f / 9.0f);
}

__device__ __forceinline__ float loss_neg(float x) {
    // target == 0: (1-alpha) * p^2 * (-log(1-p))
    float p = fminf(fmaxf(x, 1e-4f), 0.9999f);
    return (1.0f - ALPHA) * p * p * (-__logf(1.0f - p));
}

__device__ __forceinline__ float loss_neg4(f4v v) {
    return loss_neg(v[0]) + loss_neg(v[1]) + loss_neg(v[2]) + loss_neg(v[3]);
}

__device__ __forceinline__ float loss_pos(float x) {
    // target == 1: alpha * (1-p)^2 * (-log(p))
    float p = fminf(fmaxf(x, 1e-4f), 0.9999f);
    float q = 1.0f - p;
    return ALPHA * q * q * (-__logf(p));
}

// Per-anchor assignment: IoU argmax vs 32 gt boxes (1 division), reg loss.
// Returns code: -1 negative (all targets 0), -2 ignore, 0..79 positive class.
__device__ __forceinline__ signed char assign_one(
    const float4 anc, const float* __restrict__ ann,
    const float4* __restrict__ regs, int b, int a,
    float& regl, int& pcount)
{
    const float ax1 = anc.x, ay1 = anc.y, ax2 = anc.z, ay2 = anc.w;
    const float areaA = (ax2 - ax1) * (ay2 - ay1);

    float bi = -1.0f;   // best inter (sentinel loses to any valid box)
    float bu = 1.0f;    // best ua
    int   bm = -1;
    #pragma unroll 2
    for (int m = 0; m < M_N; ++m) {
        const float gx1 = ann[m * 5 + 0];
        const float gy1 = ann[m * 5 + 1];
        const float gx2 = ann[m * 5 + 2];
        const float gy2 = ann[m * 5 + 3];
        const bool valid = (ann[m * 5 + 4] != -1.0f);
        float iw = fminf(ax2, gx2) - fmaxf(ax1, gx1);
        float ih = fminf(ay2, gy2) - fmaxf(ay1, gy1);
        iw = fmaxf(iw, 0.0f);
        ih = fmaxf(ih, 0.0f);
        const float inter = iw * ih;
        const float areaB = (gx2 - gx1) * (gy2 - gy1);
        const float ua = fmaxf(areaA + areaB - inter, 1e-8f);
        // iou_m > iou_best  <=>  inter*bu > bi*ua   (ua,bu > 0)
        const bool better = valid && (inter * bu > bi * ua);
        if (better) { bi = inter; bu = ua; bm = m; }
    }

    const float iouMax = (bm >= 0) ? (bi / bu) : -1.0f;
    const bool positive = (iouMax >= 0.5f);

    if (positive) {
        pcount += 1;
        const float aw  = ax2 - ax1;
        const float ah  = ay2 - ay1;
        const float acx = ax1 + 0.5f * aw;
        const float acy = ay1 + 0.5f * ah;
        const float gx1 = ann[bm * 5 + 0];
        const float gy1 = ann[bm * 5 + 1];
        const float gx2 = ann[bm * 5 + 2];
        const float gy2 = ann[bm * 5 + 3];
        float gw = gx2 - gx1;
        float gh = gy2 - gy1;
        const float gcx = gx1 + 0.5f * gw;
        const float gcy = gy1 + 0.5f * gh;
        gw = fmaxf(gw, 1.0f);
        gh = fmaxf(gh, 1.0f);
        const float t0 = ((gcx - acx) / aw) * 10.0f;  // / 0.1
        const float t1 = ((gcy - acy) / ah) * 10.0f;
        const float t2 = __logf(gw / aw) * 5.0f;      // / 0.2
        const float t3 = __logf(gh / ah) * 5.0f;
        const float4 rg = regs[(size_t)b * A_N + a];
        regl += smooth_l1(t0 - rg.x) + smooth_l1(t1 - rg.y) +
                smooth_l1(t2 - rg.z) + smooth_l1(t3 - rg.w);
    }

    if (iouMax < 0.4f) return -1;
    if (positive)      return (signed char)(int)ann[bm * 5 + 4];
    return -2;
}

// ---------------------------------------------------------------------------
// Fused kernel:
//   prefetch iter-0 -> phase 1 assignment (LDS mask) -> phase 2 corrections
//   -> phase 3 ping-pong double-buffered branchless masked focal stream
// ---------------------------------------------------------------------------
__global__ __launch_bounds__(BLK, 4) void fused_kernel(
    const float* __restrict__ cls,           // [B,A,C]
    const float* __restrict__ regressions,   // [B,A,4]
    const float* __restrict__ anchors,       // [A,4]
    const float* __restrict__ annotations,   // [B,M,5]
    float* __restrict__ clsPart,             // [B*NBLK]
    float* __restrict__ regPart,             // [B*NBLK]
    float* __restrict__ nposPart)            // [B*NBLK]
{
    const int b    = blockIdx.y;
    const int base = blockIdx.x * APB;                 // first anchor of block
    const int nA   = min(APB, A_N - base);             // anchors in this block
    const float* __restrict__ ann = annotations + (size_t)b * M_N * 5; // uniform
    const float4* __restrict__ regs = (const float4*)regressions;

    __shared__ signed char scode[APB];
    __shared__ float       smask[APB];

    const int t    = threadIdx.x;
    const int wave = t >> 6;
    const int lane = t & 63;
    const bool full = (nA == APB);

    const float* __restrict__ rowbase = cls + (size_t)(b * A_N + base) * C_N;
    const f4v* __restrict__ src = (const f4v*)rowbase;
    // per-wave contiguous segment: idx(it,u) = it*1024 + wave*256 + u*64 + lane
    const f4v* __restrict__ pw = src + wave * (64 * U) + lane;
    const int widx0 = wave * (64 * U) + lane;          // idx at it=0,u=0

    // ---- prefetch iteration 0 into registers (hidden under phase 1) ----
    f4v vA[U], vB[U];
    if (full) {
        #pragma unroll
        for (int u = 0; u < U; ++u) vA[u] = ntload(pw + u * 64);
    }

    // ---- phase 1: assignment, 2 anchors per thread ----
    float regl = 0.0f;
    int   pcnt = 0;
    #pragma unroll 1
    for (int s = 0; s < APB; s += BLK) {
        const int li = s + t;
        const int a  = base + li;
        signed char c = -2;  // out-of-range / ignore
        if (li < nA) {
            const float4 anc = ((const float4*)anchors)[a];
            c = assign_one(anc, ann, regs, b, a, regl, pcnt);
        }
        scode[li] = c;
        smask[li] = (c != -2) ? 1.0f : 0.0f;
    }
    __syncthreads();

    float csum = 0.0f;

    // ---- phase 2: positive one-hot corrections (rare scalar reads) ----
    #pragma unroll 1
    for (int s = 0; s < APB; s += BLK) {
        const int li = s + t;
        const int code = scode[li];
        if (code >= 0) {
            const float x = rowbase[(size_t)li * C_N + code];
            csum += loss_pos(x) - loss_neg(x);
        }
    }

    // ---- phase 3: ping-pong double-buffered masked stream ----
    if (full) {
        #pragma unroll 1
        for (int it2 = 0; it2 < NIT / 2; ++it2) {
            const int it = it2 * 2;
            // issue loads for it+1 into B while consuming A
            #pragma unroll
            for (int u = 0; u < U; ++u)
                vB[u] = ntload(pw + (it + 1) * F4_PER_IT + u * 64);
            #pragma unroll
            for (int u = 0; u < U; ++u) {
                const unsigned idx = (unsigned)(it * F4_PER_IT + widx0 + u * 64);
                csum += smask[idx / 20u] * loss_neg4(vA[u]);
            }
            // issue loads for it+2 into A while consuming B
            if (it + 2 < NIT) {
                #pragma unroll
                for (int u = 0; u < U; ++u)
                    vA[u] = ntload(pw + (it + 2) * F4_PER_IT + u * 64);
            }
            #pragma unroll
            for (int u = 0; u < U; ++u) {
                const unsigned idx = (unsigned)((it + 1) * F4_PER_IT + widx0 + u * 64);
                csum += smask[idx / 20u] * loss_neg4(vB[u]);
            }
        }
    } else {
        // tail block: simple masked loop
        const int nF4 = nA * F4PA;
        for (int idx = t; idx < nF4; idx += BLK) {
            const f4v v = src[idx];
            csum += smask[(unsigned)idx / 20u] * loss_neg4(v);
        }
    }

    // ---- block reduce (deterministic, one write per block) ----
    float r = regl, p = (float)pcnt, c = csum;
    #pragma unroll
    for (int off = 32; off; off >>= 1) {
        r += __shfl_down(r, off);
        p += __shfl_down(p, off);
        c += __shfl_down(c, off);
    }
    __shared__ float wr[BLK / 64], wp[BLK / 64], wc[BLK / 64];
    if (lane == 0) { wr[wave] = r; wp[wave] = p; wc[wave] = c; }
    __syncthreads();
    if (t == 0) {
        float rr = 0.0f, pp = 0.0f, cc = 0.0f;
        #pragma unroll
        for (int w = 0; w < BLK / 64; ++w) { rr += wr[w]; pp += wp[w]; cc += wc[w]; }
        const int pidx = b * NBLK + blockIdx.x;
        clsPart[pidx]  = cc;
        regPart[pidx]  = rr;
        nposPart[pidx] = pp;
    }
}

// ---------------------------------------------------------------------------
// Finalize: one wave per image, shfl reduce of NBLK partials -> two scalars
// ---------------------------------------------------------------------------
__global__ __launch_bounds__(64 * B_IMG) void finalize_kernel(
    const float* __restrict__ annotations,
    const float* __restrict__ clsPart,
    const float* __restrict__ regPart,
    const float* __restrict__ nposPart,
    float* __restrict__ out)
{
    const int w    = threadIdx.x >> 6;   // image
    const int lane = threadIdx.x & 63;

    float c = 0.0f, r = 0.0f, p = 0.0f;
    for (int i = lane; i < NBLK; i += 64) {
        const int idx = w * NBLK + i;
        c += clsPart[idx];
        r += regPart[idx];
        p += nposPart[idx];
    }
    #pragma unroll
    for (int off = 32; off; off >>= 1) {
        c += __shfl_down(c, off);
        r += __shfl_down(r, off);
        p += __shfl_down(p, off);
    }

    __shared__ float sc[B_IMG], sr[B_IMG];
    if (lane == 0) {
        bool has = false;
        for (int m = 0; m < M_N; ++m)
            has = has || (annotations[(size_t)w * M_N * 5 + m * 5 + 4] != -1.0f);
        const float cl = c / fmaxf(p, 1.0f);
        const float rl = (p > 0.0f) ? r / (p * 4.0f) : 0.0f;
        sc[w] = has ? cl : 0.0f;
        sr[w] = has ? rl : 0.0f;
    }
    __syncthreads();
    if (threadIdx.x == 0) {
        float ca = 0.0f, ra = 0.0f;
        #pragma unroll
        for (int i = 0; i < B_IMG; ++i) { ca += sc[i]; ra += sr[i]; }
        out[0] = ca * (1.0f / B_IMG);
        out[1] = ra * (1.0f / B_IMG);
    }
}

// ---------------------------------------------------------------------------
// Launch
// ---------------------------------------------------------------------------
extern "C" void kernel_launch(void* const* d_in, const int* in_sizes, int n_in,
                              void* d_out, int out_size, void* d_ws, size_t ws_size,
                              hipStream_t stream) {
    const float* classifications = (const float*)d_in[0]; // [B,A,C]
    const float* regressions     = (const float*)d_in[1]; // [B,A,4]
    const float* anchors         = (const float*)d_in[2]; // [1,A,4]
    const float* annotations     = (const float*)d_in[3]; // [B,M,5]
    float* out = (float*)d_out;                           // [2]

    // Workspace: partials written exactly once per call -> no init pass
    float* clsPart  = (float*)d_ws;                        // B*NBLK
    float* regPart  = clsPart + (size_t)B_IMG * NBLK;      // B*NBLK
    float* nposPart = regPart + (size_t)B_IMG * NBLK;      // B*NBLK

    fused_kernel<<<dim3(NBLK, B_IMG), BLK, 0, stream>>>(
        classifications, regressions, anchors, annotations,
        clsPart, regPart, nposPart);

    finalize_kernel<<<1, 64 * B_IMG, 0, stream>>>(
        annotations, clsPart, regPart, nposPart, out);
}